// Round 1
// baseline (84.317 us; speedup 1.0000x reference)
//
#include <hip/hip_runtime.h>
#include <cmath>

#define H_ 128
#define W_ 128
#define P_ (H_ * W_)
#define BIGF 1e10f

struct Cam {
    float ex, ey, ez;
    float r00, r01, r02, r10, r11, r12, r20, r21, r22;
};

__global__ __launch_bounds__(256) void prep_faces(
    const float* __restrict__ verts, const int* __restrict__ faces,
    int F, Cam cam, float* __restrict__ rec) {
#pragma clang fp contract(off)
    int f = blockIdx.x * blockDim.x + threadIdx.x;
    if (f >= F) return;
    float tx[3], ty[3], tz[3];
    for (int k = 0; k < 3; ++k) {
        int vi = faces[f * 3 + k];
        float vx = verts[vi * 3 + 0];
        float vy = verts[vi * 3 + 1];
        float vz = verts[vi * 3 + 2];
        float dx = vx - cam.ex, dy = vy - cam.ey, dz = vz - cam.ez;
        tx[k] = (dx * cam.r00 + dy * cam.r01) + dz * cam.r02;
        ty[k] = (dx * cam.r10 + dy * cam.r11) + dz * cam.r12;
        tz[k] = (dx * cam.r20 + dy * cam.r21) + dz * cam.r22;
    }
    float a0 = tx[0], a1 = ty[0], b0 = tx[1], b1 = ty[1], c0 = tx[2], c1 = ty[2];
    float area = (b0 - a0) * (c1 - a1) - (b1 - a1) * (c0 - a0);
    float ab = fabsf(area);
    float sa = (ab < 1e-8f) ? 1e-8f : area;
    float valid = (ab >= 1e-8f) ? 1.0f : 0.0f;
    float* r = rec + (size_t)f * 12;
    r[0] = a0; r[1] = a1; r[2] = b0; r[3] = b1; r[4] = c0; r[5] = c1;
    r[6] = tz[0]; r[7] = tz[1]; r[8] = tz[2]; r[9] = sa; r[10] = valid; r[11] = 0.0f;
}

__global__ __launch_bounds__(256) void raster(
    const float* __restrict__ rec, int F, int fpc,
    float* __restrict__ bestdArr, int* __restrict__ bestfArr) {
#pragma clang fp contract(off)
    int pid = blockIdx.x * blockDim.x + threadIdx.x;
    int chunk = blockIdx.y;
    int row = pid >> 7, col = pid & 127;
    float px = ((col + 0.5f) / 128.0f) * 2.0f - 1.0f;
    float py = 1.0f - ((row + 0.5f) / 128.0f) * 2.0f;
    int f0 = chunk * fpc;
    int f1 = min(F, f0 + fpc);
    float bestd = BIGF;
    int bestf = 0;
    for (int f = f0; f < f1; ++f) {
        const float* r = rec + (size_t)f * 12;
        float a0 = r[0], a1 = r[1], b0 = r[2], b1 = r[3], c0 = r[4], c1 = r[5];
        float z0 = r[6], z1 = r[7], z2 = r[8], sa = r[9], valid = r[10];
        float w0n = (c0 - b0) * (py - b1) - (c1 - b1) * (px - b0);
        float w1n = (a0 - c0) * (py - c1) - (a1 - c1) * (px - c0);
        float w2n = (b0 - a0) * (py - a1) - (b1 - a1) * (px - a0);
        bool ins;
        if (sa > 0.0f) ins = (w0n >= 0.0f) & (w1n >= 0.0f) & (w2n >= 0.0f);
        else           ins = (w0n <= 0.0f) & (w1n <= 0.0f) & (w2n <= 0.0f);
        ins = ins && (valid != 0.0f);
        if (ins) {
            float w0 = w0n / sa, w1 = w1n / sa, w2 = w2n / sa;
            float d = (w0 * z0 + w1 * z1) + w2 * z2;
            if (d < bestd) { bestd = d; bestf = f; }
        }
    }
    int o = chunk * P_ + pid;
    bestdArr[o] = bestd;
    bestfArr[o] = bestf;
}

__global__ __launch_bounds__(256) void shade(
    const float* __restrict__ rec, const float* __restrict__ tex,
    const float* __restrict__ ref, const float* __restrict__ bestdArr,
    const int* __restrict__ bestfArr, int nchunk,
    double* __restrict__ partials) {
#pragma clang fp contract(off)
    int pid = blockIdx.x * blockDim.x + threadIdx.x;
    int row = pid >> 7, col = pid & 127;
    float px = ((col + 0.5f) / 128.0f) * 2.0f - 1.0f;
    float py = 1.0f - ((row + 0.5f) / 128.0f) * 2.0f;
    float bestd = BIGF;
    int bestf = 0;
    for (int c = 0; c < nchunk; ++c) {
        float d = bestdArr[c * P_ + pid];
        if (d < bestd) { bestd = d; bestf = bestfArr[c * P_ + pid]; }
    }
    bool hit = bestd < 5e9f;
    const float* r = rec + (size_t)bestf * 12;
    float a0 = r[0], a1 = r[1], b0 = r[2], b1 = r[3], c0 = r[4], c1 = r[5], sa = r[9];
    float u0 = ((c0 - b0) * (py - b1) - (c1 - b1) * (px - b0)) / sa;
    float u1 = ((a0 - c0) * (py - c1) - (a1 - c1) * (px - c0)) / sa;
    float u2 = ((b0 - a0) * (py - a1) - (b1 - a1) * (px - a0)) / sa;
    float w0 = fminf(fmaxf(u0, 0.0f), 1.0f);
    float w1 = fminf(fmaxf(u1, 0.0f), 1.0f);
    float w2 = fminf(fmaxf(u2, 0.0f), 1.0f);
    float s = ((w0 + w1) + w2) + 1e-8f;
    float n0 = w0 / s, n1 = w1 / s, n2 = w2 / s;
    float p0 = n0 * 3.0f, p1 = n1 * 3.0f, p2 = n2 * 3.0f;
    int l0 = (int)floorf(p0); l0 = min(max(l0, 0), 2);
    int l1 = (int)floorf(p1); l1 = min(max(l1, 0), 2);
    int l2 = (int)floorf(p2); l2 = min(max(l2, 0), 2);
    float fr0 = p0 - (float)l0;
    float fr1 = p1 - (float)l1;
    float fr2 = p2 - (float)l2;
    const float* tb = tex + (size_t)bestf * 192;
    float cr = 0.0f, cg = 0.0f, cb = 0.0f;
    for (int di = 0; di < 2; ++di)
        for (int dj = 0; dj < 2; ++dj)
            for (int dk = 0; dk < 2; ++dk) {
                float wx = di ? fr0 : (1.0f - fr0);
                float wy = dj ? fr1 : (1.0f - fr1);
                float wz = dk ? fr2 : (1.0f - fr2);
                float wgt = (wx * wy) * wz;
                int off = (((l0 + di) * 4 + (l1 + dj)) * 4 + (l2 + dk)) * 3;
                cr = cr + wgt * tanhf(tb[off + 0]);
                cg = cg + wgt * tanhf(tb[off + 1]);
                cb = cb + wgt * tanhf(tb[off + 2]);
            }
    double acc = 0.0;
    {
        float fc = hit ? cr : 0.0f;
        float d = fc - ref[0 * P_ + pid];
        acc += (double)(d * d);
        fc = hit ? cg : 0.0f;
        d = fc - ref[1 * P_ + pid];
        acc += (double)(d * d);
        fc = hit ? cb : 0.0f;
        d = fc - ref[2 * P_ + pid];
        acc += (double)(d * d);
    }
    for (int off = 32; off > 0; off >>= 1) acc += __shfl_down(acc, off);
    __shared__ double lsum[4];
    int lane = threadIdx.x & 63, wv = threadIdx.x >> 6;
    if (lane == 0) lsum[wv] = acc;
    __syncthreads();
    if (threadIdx.x == 0) {
        partials[blockIdx.x] = ((lsum[0] + lsum[1]) + lsum[2]) + lsum[3];
    }
}

__global__ void finalize(const double* __restrict__ partials, int n, float* __restrict__ out) {
    double t = 0.0;
    for (int i = 0; i < n; ++i) t += partials[i];
    out[0] = (float)t;
}

extern "C" void kernel_launch(void* const* d_in, const int* in_sizes, int n_in,
                              void* d_out, int out_size, void* d_ws, size_t ws_size,
                              hipStream_t stream) {
    const float* vertices = (const float*)d_in[0];
    const float* textures = (const float*)d_in[1];
    const float* image_ref = (const float*)d_in[2];
    const int* faces = (const int*)d_in[3];
    int F = in_sizes[3] / 3;

    // Camera computed on host in f32, mirroring reference _look_at exactly.
    float az = (float)(90.0 * M_PI / 180.0);
    float el = 0.0f;
    float ce = cosf(el), se = sinf(el);
    float sz = sinf(az), cz = cosf(az);
    const float DIST = 2.732f;
    float ex = DIST * (ce * sz);
    float ey = DIST * se;
    float ez = DIST * (-(ce * cz));
    float nrm = sqrtf((ex * ex + ey * ey) + ez * ez);
    float z0 = -ex / nrm, z1 = -ey / nrm, z2 = -ez / nrm;
    // x = cross(up, z), up = (0,1,0)
    float x0 = 1.0f * z2 - 0.0f * z1;
    float x1 = 0.0f * z0 - 0.0f * z2;
    float x2 = 0.0f * z1 - 1.0f * z0;
    float xn = sqrtf((x0 * x0 + x1 * x1) + x2 * x2);
    x0 /= xn; x1 /= xn; x2 /= xn;
    // y = cross(z, x)
    float y0 = z1 * x2 - z2 * x1;
    float y1 = z2 * x0 - z0 * x2;
    float y2 = z0 * x1 - z1 * x0;
    Cam cam{ex, ey, ez, x0, x1, x2, y0, y1, y2, z0, z1, z2};

    // Workspace layout
    size_t recB = (size_t)F * 12 * sizeof(float);
    size_t off1 = (recB + 255) & ~(size_t)255;
    int nchunk = 16;
    while (nchunk > 1 &&
           off1 + (size_t)nchunk * P_ * 8 + 512 > ws_size)
        nchunk >>= 1;
    float* rec = (float*)d_ws;
    float* bestd = (float*)((char*)d_ws + off1);
    int* bestf = (int*)((char*)d_ws + off1 + (size_t)nchunk * P_ * 4);
    double* partials = (double*)((char*)d_ws + off1 + (size_t)nchunk * P_ * 8);
    int fpc = (F + nchunk - 1) / nchunk;

    hipLaunchKernelGGL(prep_faces, dim3((F + 255) / 256), dim3(256), 0, stream,
                       vertices, faces, F, cam, rec);
    hipLaunchKernelGGL(raster, dim3(P_ / 256, nchunk), dim3(256), 0, stream,
                       rec, F, fpc, bestd, bestf);
    hipLaunchKernelGGL(shade, dim3(P_ / 256), dim3(256), 0, stream,
                       rec, textures, image_ref, bestd, bestf, nchunk, partials);
    hipLaunchKernelGGL(finalize, dim3(1), dim3(1), 0, stream,
                       partials, P_ / 256, (float*)d_out);
}

// Round 2
// 62.899 us; speedup vs baseline: 1.3405x; 1.3405x over previous
//
#include <hip/hip_runtime.h>
#include <cmath>

#define H_ 128
#define W_ 128
#define P_ (H_ * W_)
#define BIGF 1e10f
#define NTX 16
#define NTY 16
#define NTILES (NTX * NTY)
#define CAP 1024
#define LDSCAP 256

struct Cam {
    float ex, ey, ez;
    float r00, r01, r02, r10, r11, r12, r20, r21, r22;
};

__global__ __launch_bounds__(256) void prep_faces(
    const float* __restrict__ verts, const int* __restrict__ faces,
    int F, Cam cam, float* __restrict__ rec,
    int* __restrict__ tileCount, int* __restrict__ tileList) {
#pragma clang fp contract(off)
    int f = blockIdx.x * blockDim.x + threadIdx.x;
    if (f >= F) return;
    float tx[3], ty[3], tz[3];
    for (int k = 0; k < 3; ++k) {
        int vi = faces[f * 3 + k];
        float vx = verts[vi * 3 + 0];
        float vy = verts[vi * 3 + 1];
        float vz = verts[vi * 3 + 2];
        float dx = vx - cam.ex, dy = vy - cam.ey, dz = vz - cam.ez;
        tx[k] = (dx * cam.r00 + dy * cam.r01) + dz * cam.r02;
        ty[k] = (dx * cam.r10 + dy * cam.r11) + dz * cam.r12;
        tz[k] = (dx * cam.r20 + dy * cam.r21) + dz * cam.r22;
    }
    float a0 = tx[0], a1 = ty[0], b0 = tx[1], b1 = ty[1], c0 = tx[2], c1 = ty[2];
    float area = (b0 - a0) * (c1 - a1) - (b1 - a1) * (c0 - a0);
    float ab = fabsf(area);
    float sa = (ab < 1e-8f) ? 1e-8f : area;
    float valid = (ab >= 1e-8f) ? 1.0f : 0.0f;
    float* r = rec + (size_t)f * 12;
    r[0] = a0; r[1] = a1; r[2] = b0; r[3] = b1; r[4] = c0; r[5] = c1;
    r[6] = tz[0]; r[7] = tz[1]; r[8] = tz[2]; r[9] = sa; r[10] = valid; r[11] = 0.0f;

    if (valid == 0.0f) return;
    // Conservative pixel bbox (expanded by 1 px to absorb any f32 edge rounding).
    float minx = fminf(fminf(a0, b0), c0), maxx = fmaxf(fmaxf(a0, b0), c0);
    float miny = fminf(fminf(a1, b1), c1), maxy = fmaxf(fmaxf(a1, b1), c1);
    int colmin = (int)ceilf((minx + 1.0f) * 64.0f - 0.5f) - 1;
    int colmax = (int)floorf((maxx + 1.0f) * 64.0f - 0.5f) + 1;
    int rowmin = (int)ceilf((1.0f - maxy) * 64.0f - 0.5f) - 1;
    int rowmax = (int)floorf((1.0f - miny) * 64.0f - 0.5f) + 1;
    colmin = max(colmin, 0); colmax = min(colmax, W_ - 1);
    rowmin = max(rowmin, 0); rowmax = min(rowmax, H_ - 1);
    if (colmin > colmax || rowmin > rowmax) return;
    int tx0 = colmin >> 3, tx1 = colmax >> 3;
    int ty0 = rowmin >> 3, ty1 = rowmax >> 3;
    for (int ty_ = ty0; ty_ <= ty1; ++ty_)
        for (int tx_ = tx0; tx_ <= tx1; ++tx_) {
            int t = ty_ * NTX + tx_;
            int slot = atomicAdd(&tileCount[t], 1);
            if (slot < CAP) tileList[t * CAP + slot] = f;
        }
}

// One block per 8x8-pixel tile: rasterize the tile's face list, shade, loss.
__global__ __launch_bounds__(64) void shade_tiles(
    const float* __restrict__ rec, const float* __restrict__ tex,
    const float* __restrict__ ref, const int* __restrict__ tileCount,
    const int* __restrict__ tileList, double* __restrict__ partials) {
#pragma clang fp contract(off)
    __shared__ float lrec[LDSCAP * 12];
    __shared__ int lfi[LDSCAP];
    int t = blockIdx.x;
    int lx = threadIdx.x & 7, ly = threadIdx.x >> 3;
    int col = (t & (NTX - 1)) * 8 + lx;
    int row = (t >> 4) * 8 + ly;
    int pid = row * W_ + col;
    float px = ((col + 0.5f) / 128.0f) * 2.0f - 1.0f;
    float py = 1.0f - ((row + 0.5f) / 128.0f) * 2.0f;
    int n = min(tileCount[t], CAP);
    const int* list = tileList + t * CAP;
    float bestd = BIGF;
    int bestf = 0;
    for (int base = 0; base < n; base += LDSCAP) {
        int cnt = min(LDSCAP, n - base);
        __syncthreads();
        for (int idx = threadIdx.x; idx < cnt; idx += 64)
            lfi[idx] = list[base + idx];
        for (int idx = threadIdx.x; idx < cnt * 12; idx += 64) {
            int i = idx / 12, w = idx - i * 12;
            lrec[idx] = rec[(size_t)lfi[i] * 12 + w];
        }
        __syncthreads();
        for (int i = 0; i < cnt; ++i) {
            int f = lfi[i];
            const float* r = lrec + i * 12;
            float a0 = r[0], a1 = r[1], b0 = r[2], b1 = r[3], c0 = r[4], c1 = r[5];
            float z0 = r[6], z1 = r[7], z2 = r[8], sa = r[9], valid = r[10];
            float w0n = (c0 - b0) * (py - b1) - (c1 - b1) * (px - b0);
            float w1n = (a0 - c0) * (py - c1) - (a1 - c1) * (px - c0);
            float w2n = (b0 - a0) * (py - a1) - (b1 - a1) * (px - a0);
            bool ins;
            if (sa > 0.0f) ins = (w0n >= 0.0f) & (w1n >= 0.0f) & (w2n >= 0.0f);
            else           ins = (w0n <= 0.0f) & (w1n <= 0.0f) & (w2n <= 0.0f);
            ins = ins && (valid != 0.0f);
            if (ins) {
                float w0 = w0n / sa, w1 = w1n / sa, w2 = w2n / sa;
                float d = (w0 * z0 + w1 * z1) + w2 * z2;
                // argmin-first tie-break: exact regardless of list order
                if (d < bestd || (d == bestd && f < bestf)) { bestd = d; bestf = f; }
            }
        }
    }
    bool hit = bestd < 5e9f;
    const float* r = rec + (size_t)bestf * 12;
    float a0 = r[0], a1 = r[1], b0 = r[2], b1 = r[3], c0 = r[4], c1 = r[5], sa = r[9];
    float u0 = ((c0 - b0) * (py - b1) - (c1 - b1) * (px - b0)) / sa;
    float u1 = ((a0 - c0) * (py - c1) - (a1 - c1) * (px - c0)) / sa;
    float u2 = ((b0 - a0) * (py - a1) - (b1 - a1) * (px - a0)) / sa;
    float w0 = fminf(fmaxf(u0, 0.0f), 1.0f);
    float w1 = fminf(fmaxf(u1, 0.0f), 1.0f);
    float w2 = fminf(fmaxf(u2, 0.0f), 1.0f);
    float s = ((w0 + w1) + w2) + 1e-8f;
    float n0 = w0 / s, n1 = w1 / s, n2 = w2 / s;
    float p0 = n0 * 3.0f, p1 = n1 * 3.0f, p2 = n2 * 3.0f;
    int l0 = (int)floorf(p0); l0 = min(max(l0, 0), 2);
    int l1 = (int)floorf(p1); l1 = min(max(l1, 0), 2);
    int l2 = (int)floorf(p2); l2 = min(max(l2, 0), 2);
    float fr0 = p0 - (float)l0;
    float fr1 = p1 - (float)l1;
    float fr2 = p2 - (float)l2;
    const float* tb = tex + (size_t)bestf * 192;
    float cr = 0.0f, cg = 0.0f, cb = 0.0f;
    for (int di = 0; di < 2; ++di)
        for (int dj = 0; dj < 2; ++dj)
            for (int dk = 0; dk < 2; ++dk) {
                float wx = di ? fr0 : (1.0f - fr0);
                float wy = dj ? fr1 : (1.0f - fr1);
                float wz = dk ? fr2 : (1.0f - fr2);
                float wgt = (wx * wy) * wz;
                int off = (((l0 + di) * 4 + (l1 + dj)) * 4 + (l2 + dk)) * 3;
                cr = cr + wgt * tanhf(tb[off + 0]);
                cg = cg + wgt * tanhf(tb[off + 1]);
                cb = cb + wgt * tanhf(tb[off + 2]);
            }
    double acc = 0.0;
    {
        float fc = hit ? cr : 0.0f;
        float d = fc - ref[0 * P_ + pid];
        acc += (double)(d * d);
        fc = hit ? cg : 0.0f;
        d = fc - ref[1 * P_ + pid];
        acc += (double)(d * d);
        fc = hit ? cb : 0.0f;
        d = fc - ref[2 * P_ + pid];
        acc += (double)(d * d);
    }
    for (int off = 32; off > 0; off >>= 1) acc += __shfl_down(acc, off);
    if (threadIdx.x == 0) partials[t] = acc;
}

__global__ void finalize(const double* __restrict__ partials, int n, float* __restrict__ out) {
    double t = 0.0;
    for (int i = 0; i < n; ++i) t += partials[i];
    out[0] = (float)t;
}

extern "C" void kernel_launch(void* const* d_in, const int* in_sizes, int n_in,
                              void* d_out, int out_size, void* d_ws, size_t ws_size,
                              hipStream_t stream) {
    const float* vertices = (const float*)d_in[0];
    const float* textures = (const float*)d_in[1];
    const float* image_ref = (const float*)d_in[2];
    const int* faces = (const int*)d_in[3];
    int F = in_sizes[3] / 3;

    // Camera computed on host in f32, mirroring reference _look_at exactly.
    float az = (float)(90.0 * M_PI / 180.0);
    float el = 0.0f;
    float ce = cosf(el), se = sinf(el);
    float sz = sinf(az), cz = cosf(az);
    const float DIST = 2.732f;
    float ex = DIST * (ce * sz);
    float ey = DIST * se;
    float ez = DIST * (-(ce * cz));
    float nrm = sqrtf((ex * ex + ey * ey) + ez * ez);
    float z0 = -ex / nrm, z1 = -ey / nrm, z2 = -ez / nrm;
    float x0 = 1.0f * z2 - 0.0f * z1;
    float x1 = 0.0f * z0 - 0.0f * z2;
    float x2 = 0.0f * z1 - 1.0f * z0;
    float xn = sqrtf((x0 * x0 + x1 * x1) + x2 * x2);
    x0 /= xn; x1 /= xn; x2 /= xn;
    float y0 = z1 * x2 - z2 * x1;
    float y1 = z2 * x0 - z0 * x2;
    float y2 = z0 * x1 - z1 * x0;
    Cam cam{ex, ey, ez, x0, x1, x2, y0, y1, y2, z0, z1, z2};

    // Workspace layout: rec | tileCount | tileList | partials
    size_t recB = ((size_t)F * 12 * sizeof(float) + 255) & ~(size_t)255;
    size_t cntB = (NTILES * sizeof(int) + 255) & ~(size_t)255;
    size_t lstB = ((size_t)NTILES * CAP * sizeof(int) + 255) & ~(size_t)255;
    float* rec = (float*)d_ws;
    int* tileCount = (int*)((char*)d_ws + recB);
    int* tileList = (int*)((char*)d_ws + recB + cntB);
    double* partials = (double*)((char*)d_ws + recB + cntB + lstB);

    hipMemsetAsync(tileCount, 0, NTILES * sizeof(int), stream);
    hipLaunchKernelGGL(prep_faces, dim3((F + 255) / 256), dim3(256), 0, stream,
                       vertices, faces, F, cam, rec, tileCount, tileList);
    hipLaunchKernelGGL(shade_tiles, dim3(NTILES), dim3(64), 0, stream,
                       rec, textures, image_ref, tileCount, tileList, partials);
    hipLaunchKernelGGL(finalize, dim3(1), dim3(1), 0, stream,
                       partials, NTILES, (float*)d_out);
}

// Round 3
// 57.656 us; speedup vs baseline: 1.4624x; 1.0909x over previous
//
#include <hip/hip_runtime.h>
#include <cmath>

#define H_ 128
#define W_ 128
#define P_ (H_ * W_)
#define BIGF 1e10f
#define NTX 16
#define NTY 16
#define NTILES (NTX * NTY)
#define CAP 1024
#define LDSCAP 256

struct Cam {
    float ex, ey, ez;
    float r00, r01, r02, r10, r11, r12, r20, r21, r22;
};

// Zero the 256 tile counters + 1 done-counter (replaces hipMemsetAsync, whose
// graph-captured fillBuffer node cost ~39 us).
__global__ __launch_bounds__(448) void zero_counts(int* __restrict__ tileCount) {
    tileCount[threadIdx.x] = 0;  // 256 tile counts + done counter + pad
}

__global__ __launch_bounds__(256) void prep_faces(
    const float* __restrict__ verts, const int* __restrict__ faces,
    int F, Cam cam, float* __restrict__ rec,
    int* __restrict__ tileCount, int* __restrict__ tileList) {
#pragma clang fp contract(off)
    int f = blockIdx.x * blockDim.x + threadIdx.x;
    if (f >= F) return;
    float tx[3], ty[3], tz[3];
    for (int k = 0; k < 3; ++k) {
        int vi = faces[f * 3 + k];
        float vx = verts[vi * 3 + 0];
        float vy = verts[vi * 3 + 1];
        float vz = verts[vi * 3 + 2];
        float dx = vx - cam.ex, dy = vy - cam.ey, dz = vz - cam.ez;
        tx[k] = (dx * cam.r00 + dy * cam.r01) + dz * cam.r02;
        ty[k] = (dx * cam.r10 + dy * cam.r11) + dz * cam.r12;
        tz[k] = (dx * cam.r20 + dy * cam.r21) + dz * cam.r22;
    }
    float a0 = tx[0], a1 = ty[0], b0 = tx[1], b1 = ty[1], c0 = tx[2], c1 = ty[2];
    float area = (b0 - a0) * (c1 - a1) - (b1 - a1) * (c0 - a0);
    float ab = fabsf(area);
    float sa = (ab < 1e-8f) ? 1e-8f : area;
    float valid = (ab >= 1e-8f) ? 1.0f : 0.0f;
    float* r = rec + (size_t)f * 12;
    r[0] = a0; r[1] = a1; r[2] = b0; r[3] = b1; r[4] = c0; r[5] = c1;
    r[6] = tz[0]; r[7] = tz[1]; r[8] = tz[2]; r[9] = sa; r[10] = valid; r[11] = 0.0f;

    if (valid == 0.0f) return;
    // Conservative pixel bbox (expanded by 1 px to absorb any f32 edge rounding).
    float minx = fminf(fminf(a0, b0), c0), maxx = fmaxf(fmaxf(a0, b0), c0);
    float miny = fminf(fminf(a1, b1), c1), maxy = fmaxf(fmaxf(a1, b1), c1);
    int colmin = (int)ceilf((minx + 1.0f) * 64.0f - 0.5f) - 1;
    int colmax = (int)floorf((maxx + 1.0f) * 64.0f - 0.5f) + 1;
    int rowmin = (int)ceilf((1.0f - maxy) * 64.0f - 0.5f) - 1;
    int rowmax = (int)floorf((1.0f - miny) * 64.0f - 0.5f) + 1;
    colmin = max(colmin, 0); colmax = min(colmax, W_ - 1);
    rowmin = max(rowmin, 0); rowmax = min(rowmax, H_ - 1);
    if (colmin > colmax || rowmin > rowmax) return;
    int tx0 = colmin >> 3, tx1 = colmax >> 3;
    int ty0 = rowmin >> 3, ty1 = rowmax >> 3;
    for (int ty_ = ty0; ty_ <= ty1; ++ty_)
        for (int tx_ = tx0; tx_ <= tx1; ++tx_) {
            int t = ty_ * NTX + tx_;
            int slot = atomicAdd(&tileCount[t], 1);
            if (slot < CAP) tileList[t * CAP + slot] = f;
        }
}

// One block per 8x8-pixel tile: rasterize the tile's face list, shade, loss.
// Last block to finish reduces the 256 partials in fixed index order (deterministic).
__global__ __launch_bounds__(64) void shade_tiles(
    const float* __restrict__ rec, const float* __restrict__ tex,
    const float* __restrict__ ref, int* __restrict__ tileCount,
    const int* __restrict__ tileList, double* __restrict__ partials,
    float* __restrict__ out) {
#pragma clang fp contract(off)
    __shared__ float lrec[LDSCAP * 12];
    __shared__ int lfi[LDSCAP];
    int t = blockIdx.x;
    int lx = threadIdx.x & 7, ly = threadIdx.x >> 3;
    int col = (t & (NTX - 1)) * 8 + lx;
    int row = (t >> 4) * 8 + ly;
    int pid = row * W_ + col;
    float px = ((col + 0.5f) / 128.0f) * 2.0f - 1.0f;
    float py = 1.0f - ((row + 0.5f) / 128.0f) * 2.0f;
    int n = min(tileCount[t], CAP);
    const int* list = tileList + t * CAP;
    float bestd = BIGF;
    int bestf = 0;
    for (int base = 0; base < n; base += LDSCAP) {
        int cnt = min(LDSCAP, n - base);
        __syncthreads();
        for (int idx = threadIdx.x; idx < cnt; idx += 64)
            lfi[idx] = list[base + idx];
        for (int idx = threadIdx.x; idx < cnt * 12; idx += 64) {
            int i = idx / 12, w = idx - i * 12;
            lrec[idx] = rec[(size_t)lfi[i] * 12 + w];
        }
        __syncthreads();
        for (int i = 0; i < cnt; ++i) {
            int f = lfi[i];
            const float* r = lrec + i * 12;
            float a0 = r[0], a1 = r[1], b0 = r[2], b1 = r[3], c0 = r[4], c1 = r[5];
            float z0 = r[6], z1 = r[7], z2 = r[8], sa = r[9], valid = r[10];
            float w0n = (c0 - b0) * (py - b1) - (c1 - b1) * (px - b0);
            float w1n = (a0 - c0) * (py - c1) - (a1 - c1) * (px - c0);
            float w2n = (b0 - a0) * (py - a1) - (b1 - a1) * (px - a0);
            bool ins;
            if (sa > 0.0f) ins = (w0n >= 0.0f) & (w1n >= 0.0f) & (w2n >= 0.0f);
            else           ins = (w0n <= 0.0f) & (w1n <= 0.0f) & (w2n <= 0.0f);
            ins = ins && (valid != 0.0f);
            if (ins) {
                float w0 = w0n / sa, w1 = w1n / sa, w2 = w2n / sa;
                float d = (w0 * z0 + w1 * z1) + w2 * z2;
                // argmin-first tie-break: exact regardless of list order
                if (d < bestd || (d == bestd && f < bestf)) { bestd = d; bestf = f; }
            }
        }
    }
    bool hit = bestd < 5e9f;
    const float* r = rec + (size_t)bestf * 12;
    float a0 = r[0], a1 = r[1], b0 = r[2], b1 = r[3], c0 = r[4], c1 = r[5], sa = r[9];
    float u0 = ((c0 - b0) * (py - b1) - (c1 - b1) * (px - b0)) / sa;
    float u1 = ((a0 - c0) * (py - c1) - (a1 - c1) * (px - c0)) / sa;
    float u2 = ((b0 - a0) * (py - a1) - (b1 - a1) * (px - a0)) / sa;
    float w0 = fminf(fmaxf(u0, 0.0f), 1.0f);
    float w1 = fminf(fmaxf(u1, 0.0f), 1.0f);
    float w2 = fminf(fmaxf(u2, 0.0f), 1.0f);
    float s = ((w0 + w1) + w2) + 1e-8f;
    float n0 = w0 / s, n1 = w1 / s, n2 = w2 / s;
    float p0 = n0 * 3.0f, p1 = n1 * 3.0f, p2 = n2 * 3.0f;
    int l0 = (int)floorf(p0); l0 = min(max(l0, 0), 2);
    int l1 = (int)floorf(p1); l1 = min(max(l1, 0), 2);
    int l2 = (int)floorf(p2); l2 = min(max(l2, 0), 2);
    float fr0 = p0 - (float)l0;
    float fr1 = p1 - (float)l1;
    float fr2 = p2 - (float)l2;
    const float* tb = tex + (size_t)bestf * 192;
    float cr = 0.0f, cg = 0.0f, cb = 0.0f;
    for (int di = 0; di < 2; ++di)
        for (int dj = 0; dj < 2; ++dj)
            for (int dk = 0; dk < 2; ++dk) {
                float wx = di ? fr0 : (1.0f - fr0);
                float wy = dj ? fr1 : (1.0f - fr1);
                float wz = dk ? fr2 : (1.0f - fr2);
                float wgt = (wx * wy) * wz;
                int off = (((l0 + di) * 4 + (l1 + dj)) * 4 + (l2 + dk)) * 3;
                cr = cr + wgt * tanhf(tb[off + 0]);
                cg = cg + wgt * tanhf(tb[off + 1]);
                cb = cb + wgt * tanhf(tb[off + 2]);
            }
    double acc = 0.0;
    {
        float fc = hit ? cr : 0.0f;
        float d = fc - ref[0 * P_ + pid];
        acc += (double)(d * d);
        fc = hit ? cg : 0.0f;
        d = fc - ref[1 * P_ + pid];
        acc += (double)(d * d);
        fc = hit ? cb : 0.0f;
        d = fc - ref[2 * P_ + pid];
        acc += (double)(d * d);
    }
    for (int off = 32; off > 0; off >>= 1) acc += __shfl_down(acc, off);
    if (threadIdx.x == 0) {
        partials[t] = acc;
        __threadfence();
        int done = atomicAdd(&tileCount[NTILES], 1);
        if (done == NTILES - 1) {
            double tot = 0.0;
            for (int i = 0; i < NTILES; ++i) tot += partials[i];
            out[0] = (float)tot;
        }
    }
}

extern "C" void kernel_launch(void* const* d_in, const int* in_sizes, int n_in,
                              void* d_out, int out_size, void* d_ws, size_t ws_size,
                              hipStream_t stream) {
    const float* vertices = (const float*)d_in[0];
    const float* textures = (const float*)d_in[1];
    const float* image_ref = (const float*)d_in[2];
    const int* faces = (const int*)d_in[3];
    int F = in_sizes[3] / 3;

    // Camera computed on host in f32, mirroring reference _look_at exactly.
    float az = (float)(90.0 * M_PI / 180.0);
    float el = 0.0f;
    float ce = cosf(el), se = sinf(el);
    float sz = sinf(az), cz = cosf(az);
    const float DIST = 2.732f;
    float ex = DIST * (ce * sz);
    float ey = DIST * se;
    float ez = DIST * (-(ce * cz));
    float nrm = sqrtf((ex * ex + ey * ey) + ez * ez);
    float z0 = -ex / nrm, z1 = -ey / nrm, z2 = -ez / nrm;
    float x0 = 1.0f * z2 - 0.0f * z1;
    float x1 = 0.0f * z0 - 0.0f * z2;
    float x2 = 0.0f * z1 - 1.0f * z0;
    float xn = sqrtf((x0 * x0 + x1 * x1) + x2 * x2);
    x0 /= xn; x1 /= xn; x2 /= xn;
    float y0 = z1 * x2 - z2 * x1;
    float y1 = z2 * x0 - z0 * x2;
    float y2 = z0 * x1 - z1 * x0;
    Cam cam{ex, ey, ez, x0, x1, x2, y0, y1, y2, z0, z1, z2};

    // Workspace layout: rec | tileCount(+done) | tileList | partials
    size_t recB = ((size_t)F * 12 * sizeof(float) + 255) & ~(size_t)255;
    size_t cntB = ((NTILES + 1) * sizeof(int) + 255) & ~(size_t)255;
    size_t lstB = ((size_t)NTILES * CAP * sizeof(int) + 255) & ~(size_t)255;
    float* rec = (float*)d_ws;
    int* tileCount = (int*)((char*)d_ws + recB);
    int* tileList = (int*)((char*)d_ws + recB + cntB);
    double* partials = (double*)((char*)d_ws + recB + cntB + lstB);

    hipLaunchKernelGGL(zero_counts, dim3(1), dim3(448), 0, stream, tileCount);
    hipLaunchKernelGGL(prep_faces, dim3((F + 255) / 256), dim3(256), 0, stream,
                       vertices, faces, F, cam, rec, tileCount, tileList);
    hipLaunchKernelGGL(shade_tiles, dim3(NTILES), dim3(64), 0, stream,
                       rec, textures, image_ref, tileCount, tileList, partials,
                       (float*)d_out);
}